// Round 2
// baseline (224.403 us; speedup 1.0000x reference)
//
#include <hip/hip_runtime.h>
#include <hip/hip_bf16.h>
#include <cstdint>

#define N_PTS 8192
#define DIM 128
#define NBLK 2080  // 64*65/2 upper-triangle tiles

// Base-2-domain circle-loss constants (gamma=256, m=0.25, folded log2(e)).
// lp_nat = (1.25-s)(0.75-s)*256 = 256 s^2 - 512 s + 240   (1.25-s>0 always)
// ln_nat = max(s+0.25,0)*(s-0.25)*256 = (s>-0.25) ? 256 s^2 - 16 : 0
#define KC2 369.3299304675746f    //  256*log2e
#define KC1 -738.6598609351493f   // -512*log2e
#define KC0 346.2468098133512f    //  240*log2e
#define KCN0 -23.083120654223414f // -16*log2e
#define NEGH -1e30f
#define LN2F 0.6931471805599453f

typedef __attribute__((ext_vector_type(8))) __bf16 bf16x8;
typedef __attribute__((ext_vector_type(4))) float f32x4;

// RNE float -> bf16 bits (inputs are finite, no NaN handling needed)
__device__ __forceinline__ unsigned short f2bf(float x) {
  unsigned int u = __float_as_uint(x);
  unsigned int r = (u + 0x7FFFu + ((u >> 16) & 1u)) >> 16;
  return (unsigned short)r;
}

// async 16B global -> LDS (linear dest: wave-uniform base + lane*16)
__device__ __forceinline__ void gll16(const unsigned short* g, unsigned short* l) {
  __builtin_amdgcn_global_load_lds(
      (const __attribute__((address_space(1))) unsigned int*)g,
      (__attribute__((address_space(3))) unsigned int*)l, 16, 0, 0);
}

// One wave per row: L2-normalize (eps=1e-12), store bf16 bits.
// Also: zero the last-block counter, pack labels to u8.
__global__ __launch_bounds__(256) void normalize_kernel(const float* __restrict__ feat,
                                                        const int* __restrict__ labels,
                                                        unsigned short* __restrict__ fb,
                                                        unsigned char* __restrict__ lab8,
                                                        unsigned int* __restrict__ cnt) {
  const int gid = blockIdx.x * 256 + threadIdx.x;
  if (gid == 0) *cnt = 0u;
  if (gid < N_PTS) lab8[gid] = (unsigned char)labels[gid];
  const int row = blockIdx.x * 4 + (threadIdx.x >> 6);
  const int lane = threadIdx.x & 63;
  const float2 v = *(const float2*)(feat + row * DIM + lane * 2);
  float ss = v.x * v.x + v.y * v.y;
#pragma unroll
  for (int o = 32; o > 0; o >>= 1) ss += __shfl_xor(ss, o);
  const float inv = 1.0f / fmaxf(sqrtf(ss), 1e-12f);
  const unsigned int pack =
      (unsigned int)f2bf(v.x * inv) | ((unsigned int)f2bf(v.y * inv) << 16);
  *(unsigned int*)(fb + row * DIM + lane * 2) = pack;
}

// 128x128 upper-triangle tile per block. LDS layout: per 128x32 slab, logical
// (row R, 8-elem chunk Q) lives at byte R*64 + (Q ^ ((R>>1)&3))*16  (XOR swizzle,
// applied by permuting the GLOBAL source; LDS dest of global_load_lds is linear).
// Last finished block merges all partials and writes softplus(lse_p+lse_n).
__global__ __launch_bounds__(256, 5) void pair_kernel(const unsigned short* __restrict__ f,
                                                      const unsigned char* __restrict__ lab8,
                                                      float4* __restrict__ partials,
                                                      unsigned int* __restrict__ cnt,
                                                      float* __restrict__ out) {
  __shared__ __align__(16) unsigned short sA[2][4096];  // 2 x (128x32) bf16
  __shared__ __align__(16) unsigned short sB[2][4096];  // total 32 KiB exactly

  // triangular decode: offset(i) = i*(129-i)/2
  const int bid = blockIdx.x;
  int tI = (int)((129.0f - sqrtf(16641.0f - 8.0f * (float)bid)) * 0.5f);
  while (tI * (129 - tI) / 2 > bid) --tI;
  while ((tI + 1) * (128 - tI) / 2 <= bid) ++tI;
  const int tJ = tI + (bid - tI * (129 - tI) / 2);

  const int t = threadIdx.x;
  const int lane = t & 63, wave = t >> 6;
  const int wr = (wave >> 1) * 64, wc = (wave & 1) * 64;
  const int rsel = lane & 15;
  // swizzled read column offset (elems); swz(R) = (R>>1)&3 == (rsel>>1)&3 here
  const int qcol = ((lane >> 4) ^ ((rsel >> 1) & 3)) * 8;

  // staging: thread t fills linear LDS chunk t (and t+256); source chunk is
  // inverse-swizzled so the read-side XOR sees the right data.
  const int r0 = t >> 2;
  const int q0 = (t & 3) ^ ((r0 >> 1) & 3);
  const int eoff = r0 * DIM + q0 * 8;
  const unsigned short* gA = f + tI * 128 * DIM + eoff;
  const unsigned short* gB = f + tJ * 128 * DIM + eoff;

#define STAGE(buf, k0)                                   \
  do {                                                   \
    gll16(gA + (k0), &sA[buf][t * 8]);                   \
    gll16(gA + (k0) + 64 * DIM, &sA[buf][2048 + t * 8]); \
    gll16(gB + (k0), &sB[buf][t * 8]);                   \
    gll16(gB + (k0) + 64 * DIM, &sB[buf][2048 + t * 8]); \
  } while (0)

  f32x4 acc[4][4];
#pragma unroll
  for (int a = 0; a < 4; ++a)
#pragma unroll
    for (int b = 0; b < 4; ++b) acc[a][b] = (f32x4){0.f, 0.f, 0.f, 0.f};

  STAGE(0, 0);
  __syncthreads();
  for (int kk = 0; kk < 4; ++kk) {
    const int cur = kk & 1;
    if (kk < 3) STAGE(cur ^ 1, (kk + 1) * 32);  // async prefetch overlaps compute
    bf16x8 fa[4], fbv[4];
#pragma unroll
    for (int x = 0; x < 4; ++x) {
      fa[x] = *(const bf16x8*)(&sA[cur][(wr + x * 16 + rsel) * 32 + qcol]);
      fbv[x] = *(const bf16x8*)(&sB[cur][(wc + x * 16 + rsel) * 32 + qcol]);
    }
#pragma unroll
    for (int tm = 0; tm < 4; ++tm)
#pragma unroll
      for (int tn = 0; tn < 4; ++tn)
        acc[tm][tn] =
            __builtin_amdgcn_mfma_f32_16x16x32_bf16(fa[tm], fbv[tn], acc[tm][tn], 0, 0, 0);
    __syncthreads();  // drains vmcnt (prefetch) + protects buffer reuse
  }
#undef STAGE

  // ---- epilogue: circle-loss logits (base-2 domain) + logsumexp ----
  // C/D mapping (16x16x32): col = lane&15, row = (lane>>4)*4 + reg
  float* redbuf = (float*)&sA[0][0];  // sA no longer needed
  const int ibase = tI * 128 + wr + (lane >> 4) * 4;
  const int jbase = tJ * 128 + wc + rsel;
  unsigned int liPack[4], lj[4];
#pragma unroll
  for (int tn = 0; tn < 4; ++tn) lj[tn] = lab8[jbase + tn * 16];
#pragma unroll
  for (int tm = 0; tm < 4; ++tm)
    liPack[tm] = *(const unsigned int*)(lab8 + ibase + tm * 16);  // 4 labels packed

  // pass 1: selected logit in-place, per-thread maxes
  float mp = NEGH, mn = NEGH;
  if (tI != tJ) {  // all 16K pairs valid (j > i globally)
#pragma unroll
    for (int tm = 0; tm < 4; ++tm)
#pragma unroll
      for (int tn = 0; tn < 4; ++tn)
#pragma unroll
        for (int r = 0; r < 4; ++r) {
          const float s = acc[tm][tn][r];
          const float w = s * KC2;
          const float lp = fmaf(s, w + KC1, KC0);
          const float ln = (s > -0.25f) ? fmaf(s, w, KCN0) : 0.f;
          const bool eq = (((liPack[tm] >> (r * 8)) & 0xFFu) == lj[tn]);
          acc[tm][tn][r] = eq ? lp : ln;
          mp = fmaxf(mp, eq ? lp : NEGH);
          mn = fmaxf(mn, eq ? NEGH : ln);
        }
  } else {  // diagonal tile: mask out j <= i
#pragma unroll
    for (int tm = 0; tm < 4; ++tm)
#pragma unroll
      for (int tn = 0; tn < 4; ++tn) {
        const int d = (jbase + tn * 16) - (ibase + tm * 16);  // valid iff d > r
#pragma unroll
        for (int r = 0; r < 4; ++r) {
          const float s = acc[tm][tn][r];
          const float w = s * KC2;
          const float lp = fmaf(s, w + KC1, KC0);
          const float ln = (s > -0.25f) ? fmaf(s, w, KCN0) : 0.f;
          const bool eq = (((liPack[tm] >> (r * 8)) & 0xFFu) == lj[tn]);
          const bool valid = d > r;
          float u = eq ? lp : ln;
          u = valid ? u : NEGH;
          acc[tm][tn][r] = u;
          mp = fmaxf(mp, (eq && valid) ? lp : NEGH);
          mn = fmaxf(mn, (!eq && valid) ? ln : NEGH);
        }
      }
  }
#pragma unroll
  for (int o = 32; o > 0; o >>= 1) {
    mp = fmaxf(mp, __shfl_xor(mp, o));
    mn = fmaxf(mn, __shfl_xor(mn, o));
  }
  if (lane == 0) { redbuf[wave] = mp; redbuf[4 + wave] = mn; }
  __syncthreads();
  // Clamp keeps exp2(NEGH - M) == 0 even when a stream is empty in this block.
  const float Mp = fmaxf(fmaxf(fmaxf(redbuf[0], redbuf[1]), fmaxf(redbuf[2], redbuf[3])), -1e28f);
  const float Mn = fmaxf(fmaxf(fmaxf(redbuf[4], redbuf[5]), fmaxf(redbuf[6], redbuf[7])), -1e28f);
  __syncthreads();  // protect redbuf before reuse for sums

  // pass 2: one exp2 per element, route to the owning stream
  float sp = 0.f, sn = 0.f;
#pragma unroll
  for (int tm = 0; tm < 4; ++tm)
#pragma unroll
    for (int tn = 0; tn < 4; ++tn)
#pragma unroll
      for (int r = 0; r < 4; ++r) {
        const bool eq = (((liPack[tm] >> (r * 8)) & 0xFFu) == lj[tn]);
        const float e = __builtin_amdgcn_exp2f(acc[tm][tn][r] - (eq ? Mp : Mn));
        sp += eq ? e : 0.f;
        sn += eq ? 0.f : e;
      }
#pragma unroll
  for (int o = 32; o > 0; o >>= 1) {
    sp += __shfl_xor(sp, o);
    sn += __shfl_xor(sn, o);
  }
  if (lane == 0) { redbuf[wave] = sp; redbuf[4 + wave] = sn; }
  __syncthreads();

  // ---- publish partial; last finished block does the final merge ----
  unsigned int* flag = (unsigned int*)&sB[0][0];
  if (t == 0) {
    partials[bid] = make_float4(Mp, redbuf[0] + redbuf[1] + redbuf[2] + redbuf[3],
                                Mn, redbuf[4] + redbuf[5] + redbuf[6] + redbuf[7]);
    __threadfence();                          // release partials (device scope)
    const unsigned int old = atomicAdd(cnt, 1u);  // device-scope RMW
    __threadfence();                          // acquire side for the last block
    flag[0] = (old == NBLK - 1) ? 1u : 0u;
  }
  __syncthreads();
  if (flag[0] == 0u) return;

  // last block: merge 2080 (m2,s2) partials for both streams
  float fmp = NEGH, fsp = 0.f, fmn = NEGH, fsn = 0.f;
  for (int i = t; i < NBLK; i += 256) {
    const float4 p = partials[i];
    {
      const float m = fmaxf(fmp, p.x);
      fsp = fsp * __builtin_amdgcn_exp2f(fmp - m) + p.y * __builtin_amdgcn_exp2f(p.x - m);
      fmp = m;
    }
    {
      const float m = fmaxf(fmn, p.z);
      fsn = fsn * __builtin_amdgcn_exp2f(fmn - m) + p.w * __builtin_amdgcn_exp2f(p.z - m);
      fmn = m;
    }
  }
  float* smp = (float*)&sA[0][0];  // 4x256 floats = 4 KiB scratch overlay
  float* ssp = smp + 256;
  float* smn = smp + 512;
  float* ssn = smp + 768;
  smp[t] = fmp; ssp[t] = fsp; smn[t] = fmn; ssn[t] = fsn;
  __syncthreads();
  for (int off = 128; off > 0; off >>= 1) {
    if (t < off) {
      {
        const float m2 = smp[t + off], s2 = ssp[t + off];
        const float m = fmaxf(smp[t], m2);
        ssp[t] = ssp[t] * __builtin_amdgcn_exp2f(smp[t] - m) + s2 * __builtin_amdgcn_exp2f(m2 - m);
        smp[t] = m;
      }
      {
        const float m2 = smn[t + off], s2 = ssn[t + off];
        const float m = fmaxf(smn[t], m2);
        ssn[t] = ssn[t] * __builtin_amdgcn_exp2f(smn[t] - m) + s2 * __builtin_amdgcn_exp2f(m2 - m);
        smn[t] = m;
      }
    }
    __syncthreads();
  }
  if (t == 0) {
    const float lsep = (smp[0] + __builtin_amdgcn_logf(ssp[0])) * LN2F;  // base-2 -> nat
    const float lsen = (smn[0] + __builtin_amdgcn_logf(ssn[0])) * LN2F;
    const float x = lsep + lsen;
    out[0] = fmaxf(x, 0.f) + log1pf(__expf(-fabsf(x)));  // stable softplus
  }
}

extern "C" void kernel_launch(void* const* d_in, const int* in_sizes, int n_in,
                              void* d_out, int out_size, void* d_ws, size_t ws_size,
                              hipStream_t stream) {
  const float* feat = (const float*)d_in[0];
  const int* labels = (const int*)d_in[1];
  float* out = (float*)d_out;

  // ws layout (fits the previous 2MB+64KB footprint):
  unsigned short* fb = (unsigned short*)d_ws;                              // 2 MiB
  char* base = (char*)d_ws + (size_t)N_PTS * DIM * 2;
  float4* partials = (float4*)base;                                        // 2080*16 = 33280 B
  unsigned int* cnt = (unsigned int*)(base + 33280);                       // 4 B
  unsigned char* lab8 = (unsigned char*)(base + 33296);                    // 8192 B

  normalize_kernel<<<N_PTS / 4, 256, 0, stream>>>(feat, labels, fb, lab8, cnt);
  pair_kernel<<<NBLK, 256, 0, stream>>>(fb, lab8, partials, cnt, out);
}

// Round 3
// 185.868 us; speedup vs baseline: 1.2073x; 1.2073x over previous
//
#include <hip/hip_runtime.h>
#include <hip/hip_bf16.h>
#include <cstdint>

#define N_PTS 8192
#define DIM 128
#define NBLK 2080  // 64*65/2 upper-triangle tiles

// Base-2-domain circle-loss constants (gamma=256, m=0.25, folded log2(e)).
// lp_nat = (1.25-s)(0.75-s)*256 = 256 s^2 - 512 s + 240   (1.25-s>0 always)
// ln_nat = max(s+0.25,0)*(s-0.25)*256 = (s>-0.25) ? 256 s^2 - 16 : 0
#define KC2 369.3299304675746f    //  256*log2e
#define KC1 -738.6598609351493f   // -512*log2e
#define KC0 346.2468098133512f    //  240*log2e
#define KCN0 -23.083120654223414f // -16*log2e
#define NEGH -1e30f
#define LN2F 0.6931471805599453f

typedef __attribute__((ext_vector_type(8))) __bf16 bf16x8;
typedef __attribute__((ext_vector_type(4))) float f32x4;

// RNE float -> bf16 bits (inputs are finite, no NaN handling needed)
__device__ __forceinline__ unsigned short f2bf(float x) {
  unsigned int u = __float_as_uint(x);
  unsigned int r = (u + 0x7FFFu + ((u >> 16) & 1u)) >> 16;
  return (unsigned short)r;
}

// async 16B global -> LDS (linear dest: wave-uniform base + lane*16)
__device__ __forceinline__ void gll16(const unsigned short* g, unsigned short* l) {
  __builtin_amdgcn_global_load_lds(
      (const __attribute__((address_space(1))) unsigned int*)g,
      (__attribute__((address_space(3))) unsigned int*)l, 16, 0, 0);
}

// One wave per row: L2-normalize (eps=1e-12), store bf16 bits.
// Also: zero the last-block counter, pack labels to u8.
__global__ __launch_bounds__(256) void normalize_kernel(const float* __restrict__ feat,
                                                        const int* __restrict__ labels,
                                                        unsigned short* __restrict__ fb,
                                                        unsigned char* __restrict__ lab8,
                                                        unsigned int* __restrict__ cnt) {
  const int gid = blockIdx.x * 256 + threadIdx.x;
  if (gid == 0) *cnt = 0u;
  if (gid < N_PTS) lab8[gid] = (unsigned char)labels[gid];
  const int row = blockIdx.x * 4 + (threadIdx.x >> 6);
  const int lane = threadIdx.x & 63;
  const float2 v = *(const float2*)(feat + row * DIM + lane * 2);
  float ss = v.x * v.x + v.y * v.y;
#pragma unroll
  for (int o = 32; o > 0; o >>= 1) ss += __shfl_xor(ss, o);
  const float inv = 1.0f / fmaxf(sqrtf(ss), 1e-12f);
  const unsigned int pack =
      (unsigned int)f2bf(v.x * inv) | ((unsigned int)f2bf(v.y * inv) << 16);
  *(unsigned int*)(fb + row * DIM + lane * 2) = pack;
}

// 128x128 upper-triangle tile per block. LDS layout: per 128x32 slab, logical
// (row R, 8-elem chunk Q) lives at byte R*64 + (Q ^ ((R>>1)&3))*16  (XOR swizzle,
// applied by permuting the GLOBAL source; LDS dest of global_load_lds is linear).
// Last finished block merges all partials and writes softplus(lse_p+lse_n).
// launch_bounds min-waves=4: VGPR cap 128 (round-1 kernel used 116; the
// (256,5) variant forced VGPR=48 and spilled acc -> 147MB scratch writes).
__global__ __launch_bounds__(256, 4) void pair_kernel(const unsigned short* __restrict__ f,
                                                      const unsigned char* __restrict__ lab8,
                                                      float4* __restrict__ partials,
                                                      unsigned int* __restrict__ cnt,
                                                      float* __restrict__ out) {
  __shared__ __align__(16) unsigned short sA[2][4096];  // 2 x (128x32) bf16
  __shared__ __align__(16) unsigned short sB[2][4096];  // total 32 KiB exactly

  // triangular decode: offset(i) = i*(129-i)/2
  const int bid = blockIdx.x;
  int tI = (int)((129.0f - sqrtf(16641.0f - 8.0f * (float)bid)) * 0.5f);
  while (tI * (129 - tI) / 2 > bid) --tI;
  while ((tI + 1) * (128 - tI) / 2 <= bid) ++tI;
  const int tJ = tI + (bid - tI * (129 - tI) / 2);

  const int t = threadIdx.x;
  const int lane = t & 63, wave = t >> 6;
  const int wr = (wave >> 1) * 64, wc = (wave & 1) * 64;
  const int rsel = lane & 15;
  // swizzled read column offset (elems); swz(R) = (R>>1)&3 == (rsel>>1)&3 here
  const int qcol = ((lane >> 4) ^ ((rsel >> 1) & 3)) * 8;

  // staging: thread t fills linear LDS chunk t (and t+256); source chunk is
  // inverse-swizzled so the read-side XOR sees the right data.
  const int r0 = t >> 2;
  const int q0 = (t & 3) ^ ((r0 >> 1) & 3);
  const int eoff = r0 * DIM + q0 * 8;
  const unsigned short* gA = f + tI * 128 * DIM + eoff;
  const unsigned short* gB = f + tJ * 128 * DIM + eoff;

#define STAGE(buf, k0)                                   \
  do {                                                   \
    gll16(gA + (k0), &sA[buf][t * 8]);                   \
    gll16(gA + (k0) + 64 * DIM, &sA[buf][2048 + t * 8]); \
    gll16(gB + (k0), &sB[buf][t * 8]);                   \
    gll16(gB + (k0) + 64 * DIM, &sB[buf][2048 + t * 8]); \
  } while (0)

  f32x4 acc[4][4];
#pragma unroll
  for (int a = 0; a < 4; ++a)
#pragma unroll
    for (int b = 0; b < 4; ++b) acc[a][b] = (f32x4){0.f, 0.f, 0.f, 0.f};

  STAGE(0, 0);
  __syncthreads();
  for (int kk = 0; kk < 4; ++kk) {
    const int cur = kk & 1;
    if (kk < 3) STAGE(cur ^ 1, (kk + 1) * 32);  // async prefetch overlaps compute
    bf16x8 fa[4], fbv[4];
#pragma unroll
    for (int x = 0; x < 4; ++x) {
      fa[x] = *(const bf16x8*)(&sA[cur][(wr + x * 16 + rsel) * 32 + qcol]);
      fbv[x] = *(const bf16x8*)(&sB[cur][(wc + x * 16 + rsel) * 32 + qcol]);
    }
#pragma unroll
    for (int tm = 0; tm < 4; ++tm)
#pragma unroll
      for (int tn = 0; tn < 4; ++tn)
        acc[tm][tn] =
            __builtin_amdgcn_mfma_f32_16x16x32_bf16(fa[tm], fbv[tn], acc[tm][tn], 0, 0, 0);
    __syncthreads();  // drains vmcnt (prefetch) + protects buffer reuse
  }
#undef STAGE

  // ---- epilogue: circle-loss logits (base-2 domain) + logsumexp ----
  // C/D mapping (16x16x32): col = lane&15, row = (lane>>4)*4 + reg
  float* redbuf = (float*)&sA[0][0];  // sA no longer needed
  const int ibase = tI * 128 + wr + (lane >> 4) * 4;
  const int jbase = tJ * 128 + wc + rsel;
  unsigned int liPack[4], lj[4];
#pragma unroll
  for (int tn = 0; tn < 4; ++tn) lj[tn] = lab8[jbase + tn * 16];
#pragma unroll
  for (int tm = 0; tm < 4; ++tm)
    liPack[tm] = *(const unsigned int*)(lab8 + ibase + tm * 16);  // 4 labels packed

  // pass 1: selected logit in-place, per-thread maxes
  float mp = NEGH, mn = NEGH;
  if (tI != tJ) {  // all 16K pairs valid (j > i globally)
#pragma unroll
    for (int tm = 0; tm < 4; ++tm)
#pragma unroll
      for (int tn = 0; tn < 4; ++tn)
#pragma unroll
        for (int r = 0; r < 4; ++r) {
          const float s = acc[tm][tn][r];
          const float w = s * KC2;
          const float lp = fmaf(s, w + KC1, KC0);
          const float ln = (s > -0.25f) ? fmaf(s, w, KCN0) : 0.f;
          const bool eq = (((liPack[tm] >> (r * 8)) & 0xFFu) == lj[tn]);
          acc[tm][tn][r] = eq ? lp : ln;
          mp = fmaxf(mp, eq ? lp : NEGH);
          mn = fmaxf(mn, eq ? NEGH : ln);
        }
  } else {  // diagonal tile: mask out j <= i
#pragma unroll
    for (int tm = 0; tm < 4; ++tm)
#pragma unroll
      for (int tn = 0; tn < 4; ++tn) {
        const int d = (jbase + tn * 16) - (ibase + tm * 16);  // valid iff d > r
#pragma unroll
        for (int r = 0; r < 4; ++r) {
          const float s = acc[tm][tn][r];
          const float w = s * KC2;
          const float lp = fmaf(s, w + KC1, KC0);
          const float ln = (s > -0.25f) ? fmaf(s, w, KCN0) : 0.f;
          const bool eq = (((liPack[tm] >> (r * 8)) & 0xFFu) == lj[tn]);
          const bool valid = d > r;
          float u = eq ? lp : ln;
          u = valid ? u : NEGH;
          acc[tm][tn][r] = u;
          mp = fmaxf(mp, (eq && valid) ? lp : NEGH);
          mn = fmaxf(mn, (!eq && valid) ? ln : NEGH);
        }
      }
  }
#pragma unroll
  for (int o = 32; o > 0; o >>= 1) {
    mp = fmaxf(mp, __shfl_xor(mp, o));
    mn = fmaxf(mn, __shfl_xor(mn, o));
  }
  if (lane == 0) { redbuf[wave] = mp; redbuf[4 + wave] = mn; }
  __syncthreads();
  // Clamp keeps exp2(NEGH - M) == 0 even when a stream is empty in this block.
  const float Mp = fmaxf(fmaxf(fmaxf(redbuf[0], redbuf[1]), fmaxf(redbuf[2], redbuf[3])), -1e28f);
  const float Mn = fmaxf(fmaxf(fmaxf(redbuf[4], redbuf[5]), fmaxf(redbuf[6], redbuf[7])), -1e28f);
  __syncthreads();  // protect redbuf before reuse for sums

  // pass 2: one exp2 per element, route to the owning stream
  float sp = 0.f, sn = 0.f;
#pragma unroll
  for (int tm = 0; tm < 4; ++tm)
#pragma unroll
    for (int tn = 0; tn < 4; ++tn)
#pragma unroll
      for (int r = 0; r < 4; ++r) {
        const bool eq = (((liPack[tm] >> (r * 8)) & 0xFFu) == lj[tn]);
        const float e = __builtin_amdgcn_exp2f(acc[tm][tn][r] - (eq ? Mp : Mn));
        sp += eq ? e : 0.f;
        sn += eq ? 0.f : e;
      }
#pragma unroll
  for (int o = 32; o > 0; o >>= 1) {
    sp += __shfl_xor(sp, o);
    sn += __shfl_xor(sn, o);
  }
  if (lane == 0) { redbuf[wave] = sp; redbuf[4 + wave] = sn; }
  __syncthreads();

  // ---- publish partial; last finished block does the final merge ----
  unsigned int* flag = (unsigned int*)&sB[0][0];
  if (t == 0) {
    partials[bid] = make_float4(Mp, redbuf[0] + redbuf[1] + redbuf[2] + redbuf[3],
                                Mn, redbuf[4] + redbuf[5] + redbuf[6] + redbuf[7]);
    __threadfence();                          // release partials (device scope)
    const unsigned int old = atomicAdd(cnt, 1u);  // device-scope RMW
    __threadfence();                          // acquire side for the last block
    flag[0] = (old == NBLK - 1) ? 1u : 0u;
  }
  __syncthreads();
  if (flag[0] == 0u) return;

  // last block: merge 2080 (m2,s2) partials for both streams
  float fmp = NEGH, fsp = 0.f, fmn = NEGH, fsn = 0.f;
  for (int i = t; i < NBLK; i += 256) {
    const float4 p = partials[i];
    {
      const float m = fmaxf(fmp, p.x);
      fsp = fsp * __builtin_amdgcn_exp2f(fmp - m) + p.y * __builtin_amdgcn_exp2f(p.x - m);
      fmp = m;
    }
    {
      const float m = fmaxf(fmn, p.z);
      fsn = fsn * __builtin_amdgcn_exp2f(fmn - m) + p.w * __builtin_amdgcn_exp2f(p.z - m);
      fmn = m;
    }
  }
  float* smp = (float*)&sA[0][0];  // 4x256 floats = 4 KiB scratch overlay
  float* ssp = smp + 256;
  float* smn = smp + 512;
  float* ssn = smp + 768;
  smp[t] = fmp; ssp[t] = fsp; smn[t] = fmn; ssn[t] = fsn;
  __syncthreads();
  for (int off = 128; off > 0; off >>= 1) {
    if (t < off) {
      {
        const float m2 = smp[t + off], s2 = ssp[t + off];
        const float m = fmaxf(smp[t], m2);
        ssp[t] = ssp[t] * __builtin_amdgcn_exp2f(smp[t] - m) + s2 * __builtin_amdgcn_exp2f(m2 - m);
        smp[t] = m;
      }
      {
        const float m2 = smn[t + off], s2 = ssn[t + off];
        const float m = fmaxf(smn[t], m2);
        ssn[t] = ssn[t] * __builtin_amdgcn_exp2f(smn[t] - m) + s2 * __builtin_amdgcn_exp2f(m2 - m);
        smn[t] = m;
      }
    }
    __syncthreads();
  }
  if (t == 0) {
    const float lsep = (smp[0] + __builtin_amdgcn_logf(ssp[0])) * LN2F;  // base-2 -> nat
    const float lsen = (smn[0] + __builtin_amdgcn_logf(ssn[0])) * LN2F;
    const float x = lsep + lsen;
    out[0] = fmaxf(x, 0.f) + log1pf(__expf(-fabsf(x)));  // stable softplus
  }
}

extern "C" void kernel_launch(void* const* d_in, const int* in_sizes, int n_in,
                              void* d_out, int out_size, void* d_ws, size_t ws_size,
                              hipStream_t stream) {
  const float* feat = (const float*)d_in[0];
  const int* labels = (const int*)d_in[1];
  float* out = (float*)d_out;

  // ws layout (fits the previous 2MB+64KB footprint):
  unsigned short* fb = (unsigned short*)d_ws;                              // 2 MiB
  char* base = (char*)d_ws + (size_t)N_PTS * DIM * 2;
  float4* partials = (float4*)base;                                        // 2080*16 = 33280 B
  unsigned int* cnt = (unsigned int*)(base + 33280);                       // 4 B
  unsigned char* lab8 = (unsigned char*)(base + 33296);                    // 8192 B

  normalize_kernel<<<N_PTS / 4, 256, 0, stream>>>(feat, labels, fb, lab8, cnt);
  pair_kernel<<<NBLK, 256, 0, stream>>>(fb, lab8, partials, cnt, out);
}

// Round 4
// 152.808 us; speedup vs baseline: 1.4685x; 1.2164x over previous
//
#include <hip/hip_runtime.h>
#include <hip/hip_bf16.h>
#include <cstdint>

#define N_PTS 8192
#define DIM 128
#define NBLK 2080  // 64*65/2 upper-triangle tiles

// Base-2-domain circle-loss constants (gamma=256, m=0.25, folded log2(e)).
// lp_nat = (1.25-s)(0.75-s)*256 = 256 s^2 - 512 s + 240   (1.25-s>0 always)
// ln_nat = max(s+0.25,0)*(s-0.25)*256 = (s>-0.25) ? 256 s^2 - 16 : 0
#define KC2 369.3299304675746f    //  256*log2e
#define KC1 -738.6598609351493f   // -512*log2e
#define KC0 346.2468098133512f    //  240*log2e
#define KCN0 -23.083120654223414f // -16*log2e
#define NEGH -1e30f
#define LN2F 0.6931471805599453f

typedef __attribute__((ext_vector_type(8))) __bf16 bf16x8;
typedef __attribute__((ext_vector_type(4))) float f32x4;

// RNE float -> bf16 bits (inputs are finite, no NaN handling needed)
__device__ __forceinline__ unsigned short f2bf(float x) {
  unsigned int u = __float_as_uint(x);
  unsigned int r = (u + 0x7FFFu + ((u >> 16) & 1u)) >> 16;
  return (unsigned short)r;
}

// async 16B global -> LDS (linear dest: wave-uniform base + lane*16)
__device__ __forceinline__ void gll16(const unsigned short* g, unsigned short* l) {
  __builtin_amdgcn_global_load_lds(
      (const __attribute__((address_space(1))) unsigned int*)g,
      (__attribute__((address_space(3))) unsigned int*)l, 16, 0, 0);
}

// 32 lanes per row (float4/lane), 8 rows per block: L2-normalize, store bf16.
// Also: zero the last-block counter, pack labels to u8.
__global__ __launch_bounds__(256) void normalize_kernel(const float* __restrict__ feat,
                                                        const int* __restrict__ labels,
                                                        unsigned short* __restrict__ fb,
                                                        unsigned char* __restrict__ lab8,
                                                        unsigned int* __restrict__ cnt) {
  const int gid = blockIdx.x * 256 + threadIdx.x;
  if (gid == 0) *cnt = 0u;
  if (gid < N_PTS) lab8[gid] = (unsigned char)labels[gid];
  const int row = blockIdx.x * 8 + (threadIdx.x >> 5);
  const int l32 = threadIdx.x & 31;
  const float4 v = *(const float4*)(feat + row * DIM + l32 * 4);
  float ss = v.x * v.x + v.y * v.y + v.z * v.z + v.w * v.w;
#pragma unroll
  for (int o = 16; o > 0; o >>= 1) ss += __shfl_xor(ss, o);  // stays in 32-group
  const float inv = 1.0f / fmaxf(sqrtf(ss), 1e-12f);
  uint2 pack;
  pack.x = (unsigned int)f2bf(v.x * inv) | ((unsigned int)f2bf(v.y * inv) << 16);
  pack.y = (unsigned int)f2bf(v.z * inv) | ((unsigned int)f2bf(v.w * inv) << 16);
  *(uint2*)(fb + row * DIM + l32 * 4) = pack;
}

// 128x128 upper-triangle tile per block. LDS layout: per 128x32 slab, logical
// (row R, 8-elem chunk Q) lives at byte R*64 + (Q ^ ((R>>1)&3))*16  (XOR swizzle,
// applied by permuting the GLOBAL source; LDS dest of global_load_lds is linear).
// Last finished block merges all partials and writes softplus(lse_p+lse_n).
// NOTE: no min-waves in launch_bounds — (256,5) forced VGPR=48 and (256,4)
// VGPR=64, both spilling acc (35-147 MB scratch writes, 2.8-3.5x slower).
// Compiler's own allocation (~116 VGPR, 4 waves/SIMD) is the proven point.
__global__ __launch_bounds__(256) void pair_kernel(const unsigned short* __restrict__ f,
                                                   const unsigned char* __restrict__ lab8,
                                                   float4* __restrict__ partials,
                                                   unsigned int* __restrict__ cnt,
                                                   float* __restrict__ out) {
  __shared__ __align__(16) unsigned short sA[2][4096];  // 2 x (128x32) bf16
  __shared__ __align__(16) unsigned short sB[2][4096];  // total 32 KiB exactly

  // triangular decode: offset(i) = i*(129-i)/2
  const int bid = blockIdx.x;
  int tI = (int)((129.0f - sqrtf(16641.0f - 8.0f * (float)bid)) * 0.5f);
  while (tI * (129 - tI) / 2 > bid) --tI;
  while ((tI + 1) * (128 - tI) / 2 <= bid) ++tI;
  const int tJ = tI + (bid - tI * (129 - tI) / 2);

  const int t = threadIdx.x;
  const int lane = t & 63, wave = t >> 6;
  const int wr = (wave >> 1) * 64, wc = (wave & 1) * 64;
  const int rsel = lane & 15;
  // swizzled read column offset (elems); swz(R) = (R>>1)&3 == (rsel>>1)&3 here
  const int qcol = ((lane >> 4) ^ ((rsel >> 1) & 3)) * 8;

  // epilogue label gathers hoisted above the K-loop: latency hides under MFMA
  const int ibase = tI * 128 + wr + (lane >> 4) * 4;
  const int jbase = tJ * 128 + wc + rsel;
  unsigned int liPack[4], lj[4];
#pragma unroll
  for (int tn = 0; tn < 4; ++tn) lj[tn] = lab8[jbase + tn * 16];
#pragma unroll
  for (int tm = 0; tm < 4; ++tm)
    liPack[tm] = *(const unsigned int*)(lab8 + ibase + tm * 16);  // 4 labels packed

  // staging: thread t fills linear LDS chunk t (and t+256); source chunk is
  // inverse-swizzled so the read-side XOR sees the right data.
  const int r0 = t >> 2;
  const int q0 = (t & 3) ^ ((r0 >> 1) & 3);
  const int eoff = r0 * DIM + q0 * 8;
  const unsigned short* gA = f + tI * 128 * DIM + eoff;
  const unsigned short* gB = f + tJ * 128 * DIM + eoff;

#define STAGE(buf, k0)                                   \
  do {                                                   \
    gll16(gA + (k0), &sA[buf][t * 8]);                   \
    gll16(gA + (k0) + 64 * DIM, &sA[buf][2048 + t * 8]); \
    gll16(gB + (k0), &sB[buf][t * 8]);                   \
    gll16(gB + (k0) + 64 * DIM, &sB[buf][2048 + t * 8]); \
  } while (0)

  f32x4 acc[4][4];
#pragma unroll
  for (int a = 0; a < 4; ++a)
#pragma unroll
    for (int b = 0; b < 4; ++b) acc[a][b] = (f32x4){0.f, 0.f, 0.f, 0.f};

  STAGE(0, 0);
  __syncthreads();
  for (int kk = 0; kk < 4; ++kk) {
    const int cur = kk & 1;
    if (kk < 3) STAGE(cur ^ 1, (kk + 1) * 32);  // async prefetch overlaps compute
    bf16x8 fa[4], fbv[4];
#pragma unroll
    for (int x = 0; x < 4; ++x) {
      fa[x] = *(const bf16x8*)(&sA[cur][(wr + x * 16 + rsel) * 32 + qcol]);
      fbv[x] = *(const bf16x8*)(&sB[cur][(wc + x * 16 + rsel) * 32 + qcol]);
    }
#pragma unroll
    for (int tm = 0; tm < 4; ++tm)
#pragma unroll
      for (int tn = 0; tn < 4; ++tn)
        acc[tm][tn] =
            __builtin_amdgcn_mfma_f32_16x16x32_bf16(fa[tm], fbv[tn], acc[tm][tn], 0, 0, 0);
    __syncthreads();  // drains vmcnt (prefetch) + protects buffer reuse
  }
#undef STAGE

  // ---- epilogue: circle-loss logits (base-2 domain) + logsumexp ----
  // C/D mapping (16x16x32): col = lane&15, row = (lane>>4)*4 + reg
  float* redbuf = (float*)&sA[0][0];  // sA no longer needed

  // pass 1: selected logit in-place, per-thread maxes
  float mp = NEGH, mn = NEGH;
  if (tI != tJ) {  // all 16K pairs valid (j > i globally)
#pragma unroll
    for (int tm = 0; tm < 4; ++tm)
#pragma unroll
      for (int tn = 0; tn < 4; ++tn)
#pragma unroll
        for (int r = 0; r < 4; ++r) {
          const float s = acc[tm][tn][r];
          const float w = s * KC2;
          const float lp = fmaf(s, w + KC1, KC0);
          const float ln = (s > -0.25f) ? fmaf(s, w, KCN0) : 0.f;
          const bool eq = (((liPack[tm] >> (r * 8)) & 0xFFu) == lj[tn]);
          acc[tm][tn][r] = eq ? lp : ln;
          mp = fmaxf(mp, eq ? lp : NEGH);
          mn = fmaxf(mn, eq ? NEGH : ln);
        }
  } else {  // diagonal tile: mask out j <= i
#pragma unroll
    for (int tm = 0; tm < 4; ++tm)
#pragma unroll
      for (int tn = 0; tn < 4; ++tn) {
        const int d = (jbase + tn * 16) - (ibase + tm * 16);  // valid iff d > r
#pragma unroll
        for (int r = 0; r < 4; ++r) {
          const float s = acc[tm][tn][r];
          const float w = s * KC2;
          const float lp = fmaf(s, w + KC1, KC0);
          const float ln = (s > -0.25f) ? fmaf(s, w, KCN0) : 0.f;
          const bool eq = (((liPack[tm] >> (r * 8)) & 0xFFu) == lj[tn]);
          const bool valid = d > r;
          float u = eq ? lp : ln;
          u = valid ? u : NEGH;
          acc[tm][tn][r] = u;
          mp = fmaxf(mp, (eq && valid) ? lp : NEGH);
          mn = fmaxf(mn, (!eq && valid) ? ln : NEGH);
        }
      }
  }
#pragma unroll
  for (int o = 32; o > 0; o >>= 1) {
    mp = fmaxf(mp, __shfl_xor(mp, o));
    mn = fmaxf(mn, __shfl_xor(mn, o));
  }
  if (lane == 0) { redbuf[wave] = mp; redbuf[4 + wave] = mn; }
  __syncthreads();
  // Clamp keeps exp2(NEGH - M) == 0 even when a stream is empty in this block.
  const float Mp = fmaxf(fmaxf(fmaxf(redbuf[0], redbuf[1]), fmaxf(redbuf[2], redbuf[3])), -1e28f);
  const float Mn = fmaxf(fmaxf(fmaxf(redbuf[4], redbuf[5]), fmaxf(redbuf[6], redbuf[7])), -1e28f);
  __syncthreads();  // protect redbuf before reuse for sums

  // pass 2: one exp2 per element, route to the owning stream
  float sp = 0.f, sn = 0.f;
#pragma unroll
  for (int tm = 0; tm < 4; ++tm)
#pragma unroll
    for (int tn = 0; tn < 4; ++tn)
#pragma unroll
      for (int r = 0; r < 4; ++r) {
        const bool eq = (((liPack[tm] >> (r * 8)) & 0xFFu) == lj[tn]);
        const float e = __builtin_amdgcn_exp2f(acc[tm][tn][r] - (eq ? Mp : Mn));
        sp += eq ? e : 0.f;
        sn += eq ? 0.f : e;
      }
#pragma unroll
  for (int o = 32; o > 0; o >>= 1) {
    sp += __shfl_xor(sp, o);
    sn += __shfl_xor(sn, o);
  }
  if (lane == 0) { redbuf[wave] = sp; redbuf[4 + wave] = sn; }
  __syncthreads();

  // ---- publish partial; last finished block does the final merge ----
  unsigned int* flag = (unsigned int*)&sB[0][0];
  if (t == 0) {
    partials[bid] = make_float4(Mp, redbuf[0] + redbuf[1] + redbuf[2] + redbuf[3],
                                Mn, redbuf[4] + redbuf[5] + redbuf[6] + redbuf[7]);
    __threadfence();                          // release partials (device scope)
    const unsigned int old = atomicAdd(cnt, 1u);  // device-scope RMW
    __threadfence();                          // acquire side for the last block
    flag[0] = (old == NBLK - 1) ? 1u : 0u;
  }
  __syncthreads();
  if (flag[0] == 0u) return;

  // last block: merge 2080 (m2,s2) partials for both streams
  float fmp = NEGH, fsp = 0.f, fmn = NEGH, fsn = 0.f;
  for (int i = t; i < NBLK; i += 256) {
    const float4 p = partials[i];
    {
      const float m = fmaxf(fmp, p.x);
      fsp = fsp * __builtin_amdgcn_exp2f(fmp - m) + p.y * __builtin_amdgcn_exp2f(p.x - m);
      fmp = m;
    }
    {
      const float m = fmaxf(fmn, p.z);
      fsn = fsn * __builtin_amdgcn_exp2f(fmn - m) + p.w * __builtin_amdgcn_exp2f(p.z - m);
      fmn = m;
    }
  }
  float* smp = (float*)&sA[0][0];  // 4x256 floats = 4 KiB scratch overlay
  float* ssp = smp + 256;
  float* smn = smp + 512;
  float* ssn = smp + 768;
  smp[t] = fmp; ssp[t] = fsp; smn[t] = fmn; ssn[t] = fsn;
  __syncthreads();
  for (int off = 128; off > 0; off >>= 1) {
    if (t < off) {
      {
        const float m2 = smp[t + off], s2 = ssp[t + off];
        const float m = fmaxf(smp[t], m2);
        ssp[t] = ssp[t] * __builtin_amdgcn_exp2f(smp[t] - m) + s2 * __builtin_amdgcn_exp2f(m2 - m);
        smp[t] = m;
      }
      {
        const float m2 = smn[t + off], s2 = ssn[t + off];
        const float m = fmaxf(smn[t], m2);
        ssn[t] = ssn[t] * __builtin_amdgcn_exp2f(smn[t] - m) + s2 * __builtin_amdgcn_exp2f(m2 - m);
        smn[t] = m;
      }
    }
    __syncthreads();
  }
  if (t == 0) {
    const float lsep = (smp[0] + __builtin_amdgcn_logf(ssp[0])) * LN2F;  // base-2 -> nat
    const float lsen = (smn[0] + __builtin_amdgcn_logf(ssn[0])) * LN2F;
    const float x = lsep + lsen;
    out[0] = fmaxf(x, 0.f) + log1pf(__expf(-fabsf(x)));  // stable softplus
  }
}

extern "C" void kernel_launch(void* const* d_in, const int* in_sizes, int n_in,
                              void* d_out, int out_size, void* d_ws, size_t ws_size,
                              hipStream_t stream) {
  const float* feat = (const float*)d_in[0];
  const int* labels = (const int*)d_in[1];
  float* out = (float*)d_out;

  // ws layout (fits the previous 2MB+64KB footprint):
  unsigned short* fb = (unsigned short*)d_ws;                              // 2 MiB
  char* base = (char*)d_ws + (size_t)N_PTS * DIM * 2;
  float4* partials = (float4*)base;                                        // 2080*16 = 33280 B
  unsigned int* cnt = (unsigned int*)(base + 33280);                       // 4 B
  unsigned char* lab8 = (unsigned char*)(base + 33296);                    // 8192 B

  normalize_kernel<<<N_PTS / 8, 256, 0, stream>>>(feat, labels, fb, lab8, cnt);
  pair_kernel<<<NBLK, 256, 0, stream>>>(fb, lab8, partials, cnt, out);
}

// Round 5
// 97.960 us; speedup vs baseline: 2.2908x; 1.5599x over previous
//
#include <hip/hip_runtime.h>
#include <hip/hip_bf16.h>
#include <cstdint>

#define N_PTS 8192
#define DIM 128
#define NBLK 2080  // 64*65/2 upper-triangle tiles

// Base-2-domain circle-loss constants (gamma=256, m=0.25, folded log2(e)).
// lp_nat = (1.25-s)(0.75-s)*256 = 256 s^2 - 512 s + 240   (1.25-s>0 always)
// ln_nat = max(s+0.25,0)*(s-0.25)*256 = (s>-0.25) ? 256 s^2 - 16 : 0
#define KC2 369.3299304675746f    //  256*log2e
#define KC1 -738.6598609351493f   // -512*log2e
#define KC0 346.2468098133512f    //  240*log2e
#define KCN0 -23.083120654223414f // -16*log2e
#define NEGH -1e30f
#define LN2F 0.6931471805599453f

typedef __attribute__((ext_vector_type(8))) __bf16 bf16x8;
typedef __attribute__((ext_vector_type(4))) float f32x4;

// RNE float -> bf16 bits (inputs are finite, no NaN handling needed)
__device__ __forceinline__ unsigned short f2bf(float x) {
  unsigned int u = __float_as_uint(x);
  unsigned int r = (u + 0x7FFFu + ((u >> 16) & 1u)) >> 16;
  return (unsigned short)r;
}

// async 16B global -> LDS (linear dest: wave-uniform base + lane*16)
__device__ __forceinline__ void gll16(const unsigned short* g, unsigned short* l) {
  __builtin_amdgcn_global_load_lds(
      (const __attribute__((address_space(1))) unsigned int*)g,
      (__attribute__((address_space(3))) unsigned int*)l, 16, 0, 0);
}

// 32 lanes per row (float4/lane), 8 rows per block: L2-normalize, store bf16.
// Also: pack labels to u8.
__global__ __launch_bounds__(256) void normalize_kernel(const float* __restrict__ feat,
                                                        const int* __restrict__ labels,
                                                        unsigned short* __restrict__ fb,
                                                        unsigned char* __restrict__ lab8) {
  const int gid = blockIdx.x * 256 + threadIdx.x;
  if (gid < N_PTS) lab8[gid] = (unsigned char)labels[gid];
  const int row = blockIdx.x * 8 + (threadIdx.x >> 5);
  const int l32 = threadIdx.x & 31;
  const float4 v = *(const float4*)(feat + row * DIM + l32 * 4);
  float ss = v.x * v.x + v.y * v.y + v.z * v.z + v.w * v.w;
#pragma unroll
  for (int o = 16; o > 0; o >>= 1) ss += __shfl_xor(ss, o);  // stays in 32-group
  const float inv = 1.0f / fmaxf(sqrtf(ss), 1e-12f);
  uint2 pack;
  pack.x = (unsigned int)f2bf(v.x * inv) | ((unsigned int)f2bf(v.y * inv) << 16);
  pack.y = (unsigned int)f2bf(v.z * inv) | ((unsigned int)f2bf(v.w * inv) << 16);
  *(uint2*)(fb + row * DIM + l32 * 4) = pack;
}

// 128x128 upper-triangle tile per block. LDS layout: per 128x32 slab, logical
// (row R, 8-elem chunk Q) lives at byte R*64 + (Q ^ ((R>>1)&3))*16  (XOR swizzle,
// applied by permuting the GLOBAL source; LDS dest of global_load_lds is linear).
// K-loop is sync-FIRST: the barrier's vmcnt(0) drains loads issued a full
// iteration earlier (hidden), and staging after the barrier is race-free
// against the previous iteration's ds_reads (round-4 post-mortem: stage-
// before-compute exposed the full load latency at every end-of-iter barrier).
// NOTE: no min-waves in launch_bounds — (256,5)/(256,4) forced VGPR 48/64 and
// spilled acc (35-147 MB scratch writes). Compiler's choice (~112) is right.
// NOTE: finalize is a separate kernel — fusing it cost ~50 us: 2080 blocks
// each paying agent-scope __threadfence (L2 writeback on gfx950) + atomic.
__global__ __launch_bounds__(256) void pair_kernel(const unsigned short* __restrict__ f,
                                                   const unsigned char* __restrict__ lab8,
                                                   float4* __restrict__ partials) {
  __shared__ __align__(16) unsigned short sA[2][4096];  // 2 x (128x32) bf16
  __shared__ __align__(16) unsigned short sB[2][4096];  // total 32 KiB exactly
  __shared__ float redbuf[8];

  // triangular decode: offset(i) = i*(129-i)/2
  const int bid = blockIdx.x;
  int tI = (int)((129.0f - sqrtf(16641.0f - 8.0f * (float)bid)) * 0.5f);
  while (tI * (129 - tI) / 2 > bid) --tI;
  while ((tI + 1) * (128 - tI) / 2 <= bid) ++tI;
  const int tJ = tI + (bid - tI * (129 - tI) / 2);

  const int t = threadIdx.x;
  const int lane = t & 63, wave = t >> 6;
  const int wr = (wave >> 1) * 64, wc = (wave & 1) * 64;
  const int rsel = lane & 15;
  // swizzled read column offset (elems); swz(R) = (R>>1)&3 == (rsel>>1)&3 here
  const int qcol = ((lane >> 4) ^ ((rsel >> 1) & 3)) * 8;

  // epilogue label gathers hoisted above the K-loop: latency hides under MFMA
  const int ibase = tI * 128 + wr + (lane >> 4) * 4;
  const int jbase = tJ * 128 + wc + rsel;
  unsigned int liPack[4], lj[4];
#pragma unroll
  for (int tn = 0; tn < 4; ++tn) lj[tn] = lab8[jbase + tn * 16];
#pragma unroll
  for (int tm = 0; tm < 4; ++tm)
    liPack[tm] = *(const unsigned int*)(lab8 + ibase + tm * 16);  // 4 labels packed

  // staging: thread t fills linear LDS chunk t (and t+256); source chunk is
  // inverse-swizzled so the read-side XOR sees the right data.
  const int r0 = t >> 2;
  const int q0 = (t & 3) ^ ((r0 >> 1) & 3);
  const int eoff = r0 * DIM + q0 * 8;
  const unsigned short* gA = f + tI * 128 * DIM + eoff;
  const unsigned short* gB = f + tJ * 128 * DIM + eoff;

#define STAGE(buf, k0)                                   \
  do {                                                   \
    gll16(gA + (k0), &sA[buf][t * 8]);                   \
    gll16(gA + (k0) + 64 * DIM, &sA[buf][2048 + t * 8]); \
    gll16(gB + (k0), &sB[buf][t * 8]);                   \
    gll16(gB + (k0) + 64 * DIM, &sB[buf][2048 + t * 8]); \
  } while (0)

  f32x4 acc[4][4];
#pragma unroll
  for (int a = 0; a < 4; ++a)
#pragma unroll
    for (int b = 0; b < 4; ++b) acc[a][b] = (f32x4){0.f, 0.f, 0.f, 0.f};

  STAGE(0, 0);  // prologue loads; drained by iter-0's barrier (exposed once)
  for (int kk = 0; kk < 4; ++kk) {
    const int cur = kk & 1;
    __syncthreads();  // vmcnt(0): drains buf[cur] loads issued LAST iter (hidden)
    if (kk < 3) STAGE(cur ^ 1, (kk + 1) * 32);  // after barrier: prev readers done
    bf16x8 fa[4], fbv[4];
#pragma unroll
    for (int x = 0; x < 4; ++x) {
      fa[x] = *(const bf16x8*)(&sA[cur][(wr + x * 16 + rsel) * 32 + qcol]);
      fbv[x] = *(const bf16x8*)(&sB[cur][(wc + x * 16 + rsel) * 32 + qcol]);
    }
#pragma unroll
    for (int tm = 0; tm < 4; ++tm)
#pragma unroll
      for (int tn = 0; tn < 4; ++tn)
        acc[tm][tn] =
            __builtin_amdgcn_mfma_f32_16x16x32_bf16(fa[tm], fbv[tn], acc[tm][tn], 0, 0, 0);
  }
#undef STAGE

  // ---- epilogue: circle-loss logits (base-2 domain) + logsumexp ----
  // C/D mapping (16x16x32): col = lane&15, row = (lane>>4)*4 + reg

  // pass 1: selected logit in-place, per-thread maxes
  float mp = NEGH, mn = NEGH;
  if (tI != tJ) {  // all 16K pairs valid (j > i globally)
#pragma unroll
    for (int tm = 0; tm < 4; ++tm)
#pragma unroll
      for (int tn = 0; tn < 4; ++tn)
#pragma unroll
        for (int r = 0; r < 4; ++r) {
          const float s = acc[tm][tn][r];
          const float w = s * KC2;
          const float lp = fmaf(s, w + KC1, KC0);
          const float ln = (s > -0.25f) ? fmaf(s, w, KCN0) : 0.f;
          const bool eq = (((liPack[tm] >> (r * 8)) & 0xFFu) == lj[tn]);
          acc[tm][tn][r] = eq ? lp : ln;
          mp = fmaxf(mp, eq ? lp : NEGH);
          mn = fmaxf(mn, eq ? NEGH : ln);
        }
  } else {  // diagonal tile: mask out j <= i
#pragma unroll
    for (int tm = 0; tm < 4; ++tm)
#pragma unroll
      for (int tn = 0; tn < 4; ++tn) {
        const int d = (jbase + tn * 16) - (ibase + tm * 16);  // valid iff d > r
#pragma unroll
        for (int r = 0; r < 4; ++r) {
          const float s = acc[tm][tn][r];
          const float w = s * KC2;
          const float lp = fmaf(s, w + KC1, KC0);
          const float ln = (s > -0.25f) ? fmaf(s, w, KCN0) : 0.f;
          const bool eq = (((liPack[tm] >> (r * 8)) & 0xFFu) == lj[tn]);
          const bool valid = d > r;
          float u = eq ? lp : ln;
          u = valid ? u : NEGH;
          acc[tm][tn][r] = u;
          mp = fmaxf(mp, (eq && valid) ? lp : NEGH);
          mn = fmaxf(mn, (!eq && valid) ? ln : NEGH);
        }
      }
  }
#pragma unroll
  for (int o = 32; o > 0; o >>= 1) {
    mp = fmaxf(mp, __shfl_xor(mp, o));
    mn = fmaxf(mn, __shfl_xor(mn, o));
  }
  if (lane == 0) { redbuf[wave] = mp; redbuf[4 + wave] = mn; }
  __syncthreads();
  // Clamp keeps exp2(NEGH - M) == 0 even when a stream is empty in this block.
  const float Mp = fmaxf(fmaxf(fmaxf(redbuf[0], redbuf[1]), fmaxf(redbuf[2], redbuf[3])), -1e28f);
  const float Mn = fmaxf(fmaxf(fmaxf(redbuf[4], redbuf[5]), fmaxf(redbuf[6], redbuf[7])), -1e28f);
  __syncthreads();  // protect redbuf before reuse for sums

  // pass 2: one exp2 per element, route to the owning stream
  float sp = 0.f, sn = 0.f;
#pragma unroll
  for (int tm = 0; tm < 4; ++tm)
#pragma unroll
    for (int tn = 0; tn < 4; ++tn)
#pragma unroll
      for (int r = 0; r < 4; ++r) {
        const bool eq = (((liPack[tm] >> (r * 8)) & 0xFFu) == lj[tn]);
        const float e = __builtin_amdgcn_exp2f(acc[tm][tn][r] - (eq ? Mp : Mn));
        sp += eq ? e : 0.f;
        sn += eq ? 0.f : e;
      }
#pragma unroll
  for (int o = 32; o > 0; o >>= 1) {
    sp += __shfl_xor(sp, o);
    sn += __shfl_xor(sn, o);
  }
  if (lane == 0) { redbuf[wave] = sp; redbuf[4 + wave] = sn; }
  __syncthreads();
  if (t == 0) {
    partials[bid] = make_float4(Mp, redbuf[0] + redbuf[1] + redbuf[2] + redbuf[3],
                                Mn, redbuf[4] + redbuf[5] + redbuf[6] + redbuf[7]);
  }
}

// Merge 2080 (m2,s2) base-2 partials for both streams; softplus(lse_p + lse_n).
__global__ __launch_bounds__(256) void finalize_kernel(const float4* __restrict__ partials,
                                                       float* __restrict__ out) {
  const int t = threadIdx.x;
  float mp = NEGH, sp = 0.f, mn = NEGH, sn = 0.f;
  for (int i = t; i < NBLK; i += 256) {
    const float4 p = partials[i];
    {
      const float m = fmaxf(mp, p.x);
      sp = sp * __builtin_amdgcn_exp2f(mp - m) + p.y * __builtin_amdgcn_exp2f(p.x - m);
      mp = m;
    }
    {
      const float m = fmaxf(mn, p.z);
      sn = sn * __builtin_amdgcn_exp2f(mn - m) + p.w * __builtin_amdgcn_exp2f(p.z - m);
      mn = m;
    }
  }
  __shared__ float smp[256], ssp[256], smn[256], ssn[256];
  smp[t] = mp; ssp[t] = sp; smn[t] = mn; ssn[t] = sn;
  __syncthreads();
  for (int off = 128; off > 0; off >>= 1) {
    if (t < off) {
      {
        const float m2 = smp[t + off], s2 = ssp[t + off];
        const float m = fmaxf(smp[t], m2);
        ssp[t] = ssp[t] * __builtin_amdgcn_exp2f(smp[t] - m) + s2 * __builtin_amdgcn_exp2f(m2 - m);
        smp[t] = m;
      }
      {
        const float m2 = smn[t + off], s2 = ssn[t + off];
        const float m = fmaxf(smn[t], m2);
        ssn[t] = ssn[t] * __builtin_amdgcn_exp2f(smn[t] - m) + s2 * __builtin_amdgcn_exp2f(m2 - m);
        smn[t] = m;
      }
    }
    __syncthreads();
  }
  if (t == 0) {
    const float lsep = (smp[0] + __builtin_amdgcn_logf(ssp[0])) * LN2F;  // base-2 -> nat
    const float lsen = (smn[0] + __builtin_amdgcn_logf(ssn[0])) * LN2F;
    const float x = lsep + lsen;
    out[0] = fmaxf(x, 0.f) + log1pf(__expf(-fabsf(x)));  // stable softplus
  }
}

extern "C" void kernel_launch(void* const* d_in, const int* in_sizes, int n_in,
                              void* d_out, int out_size, void* d_ws, size_t ws_size,
                              hipStream_t stream) {
  const float* feat = (const float*)d_in[0];
  const int* labels = (const int*)d_in[1];
  float* out = (float*)d_out;

  unsigned short* fb = (unsigned short*)d_ws;                              // 2 MiB
  char* base = (char*)d_ws + (size_t)N_PTS * DIM * 2;
  float4* partials = (float4*)base;                                        // 2080*16 = 33280 B
  unsigned char* lab8 = (unsigned char*)(base + 33280);                    // 8192 B

  normalize_kernel<<<N_PTS / 8, 256, 0, stream>>>(feat, labels, fb, lab8);
  pair_kernel<<<NBLK, 256, 0, stream>>>(fb, lab8, partials);
  finalize_kernel<<<1, 256, 0, stream>>>(partials, out);
}